// Round 10
// baseline (288.583 us; speedup 1.0000x reference)
//
#include <hip/hip_runtime.h>
#include <hip/hip_fp16.h>
#include <stdint.h>

// GCN: x[N,8] -> GCNConv(8,64)+ReLU -> GCNConv(64,12)+ReLU -> segment_max(G) -> @Wl+bl -> log_softmax
// N=200000, E=1600000, G=2000. fp32 params; indices int32.
//
// R21: DISPATCH-COUNT attack (non-cooperative). Evidence: 8 consecutive
// in-kernel nulls (R14,R16,R17,R19,R20 micro-opts all +-0); unprofiled-delta
// decomposition gives binA+binB=63us, agg1f=21us, leaving ~92us for
// agg2+head+memset+BOUNDARIES -> ~30-50us of launch overhead over 6
// dispatches is the only unattacked bucket. This round: agg1+agg2+head fused
// into ONE kernel with a device-scope spin barrier. Co-residency GUARANTEED:
// __launch_bounds__(256,3) + LDS=0 -> 3 blocks/CU x 256 CU = 768 resident;
// grid=768 exactly, grid-stride over 782 tiles -> arrive-and-wait barrier is
// deadlock-free. Phase bodies byte-identical to R20b (isolate the variable).
// pooled zeroing moved into binB; memset shrinks to bcursor+bar (~3KB).
// Dispatches: memset + binA + binB + aggf = 4 (was 6).
// Algebra (R3): xd=x*dis ; z[t]=dis[t]*(xd[t]+sum xd[src]) ;
// y2=(relu(z@W1+b1)@W2)*dis ; h2[t]=relu(dis[t]*(y2[t]+sum y2[src])+b2) ;
// pool-max per graph ; head.
// R14 lesson: MLP weight indices wave-uniform -> s_load scalarization.
// R19 lesson: node-parallel gathers. R15 lesson: NO cooperative launch.

constexpr int IN_DIM = 8;
constexpr int H1 = 64;
constexpr int H2 = 12;
constexpr int NPB = 256;      // nodes per bucket (bucket = dst >> 8)
constexpr int NBK = 782;      // ceil(200000 / 256)
constexpr int CAP = 2560;     // per-bucket capacity (avg 2048, sd ~45 -> 11 sigma)
constexpr int CHUNK = 2048;   // edges per binA block
constexpr int SLOTS = 16;     // padded csr slots per node
constexpr int AGRID = 768;    // fused-agg grid: 3 blocks/CU x 256 CUs (guaranteed resident)

__device__ __forceinline__ void acc_row8(float* acc, int4 rv) {
    const __half2* h = (const __half2*)&rv;
#pragma unroll
    for (int q = 0; q < 4; ++q) {
        float2 f = __half22float2(h[q]);
        acc[2 * q] += f.x; acc[2 * q + 1] += f.y;
    }
}

__device__ __forceinline__ void acc_row32(float* acc, int4 ra, int4 rb) {
    const __half2* ha = (const __half2*)&ra;
    const __half2* hb = (const __half2*)&rb;
#pragma unroll
    for (int q = 0; q < 4; ++q) {
        float2 f = __half22float2(ha[q]);
        acc[2 * q] += f.x; acc[2 * q + 1] += f.y;
    }
#pragma unroll
    for (int q = 0; q < 2; ++q) {
        float2 f = __half22float2(hb[q]);
        acc[8 + 2 * q] += f.x; acc[9 + 2 * q] += f.y;
    }
}

// ---------------- pass A: bucket-sorted staging -> run-coalesced pair writes ----------
__global__ void __launch_bounds__(256) k_binA(
        const int* __restrict__ src, const int* __restrict__ dst,
        uint32_t* __restrict__ pairs, int* __restrict__ bcursor, int ne) {
    __shared__ int s_cnt[NBK];        // per-bucket count
    __shared__ int s_start[NBK];      // block-local exclusive starts
    __shared__ int s_gb[NBK];         // global run base
    __shared__ int s_wsum[4];         // per-wave scan totals
    __shared__ uint32_t s_img[CHUNK]; // bucket-sorted pairs (8 KB)
    __shared__ uint16_t s_bkt[CHUNK]; // bucket id per slot (4 KB)
    int t = threadIdx.x;
    int lane = t & 63, wv = t >> 6;
    for (int i = t; i < NBK; i += 256) s_cnt[i] = 0;
    __syncthreads();
    int e0 = blockIdx.x * CHUNK;
    int cntblk = min(CHUNK, ne - e0);
    int rec[8];
#pragma unroll
    for (int i = 0; i < 8; ++i) {
        int e = e0 + i * 256 + t;
        rec[i] = -1;
        if (e < ne) {
            int d = __builtin_nontemporal_load(&dst[e]);
            int b = d >> 8;                                  // 10 bits
            int off = atomicAdd(&s_cnt[b], 1);               // 11 bits
            rec[i] = (off << 18) | ((d & 255) << 10) | b;    // 12|8|10
        }
    }
    __syncthreads();
    // exclusive scan of s_cnt[782] (pad to 1024), 4 elems/thread:
    // thread-local prefix + wave shfl scan + cross-wave combine (2 barriers)
    int b4 = t * 4;
    int v0 = (b4 < NBK) ? s_cnt[b4] : 0;
    int v1 = (b4 + 1 < NBK) ? s_cnt[b4 + 1] : 0;
    int v2 = (b4 + 2 < NBK) ? s_cnt[b4 + 2] : 0;
    int v3 = (b4 + 3 < NBK) ? s_cnt[b4 + 3] : 0;
    int p1 = v0, p2 = v0 + v1, p3 = v0 + v1 + v2, tot = p3 + v3;
    int inc = tot;
#pragma unroll
    for (int off = 1; off < 64; off <<= 1) {
        int u = __shfl_up(inc, off, 64);
        if (lane >= off) inc += u;
    }
    if (lane == 63) s_wsum[wv] = inc;
    __syncthreads();
    int wpre = 0;
#pragma unroll
    for (int w = 0; w < 3; ++w) wpre += (w < wv) ? s_wsum[w] : 0;
    int ex = wpre + inc - tot;
    if (b4 < NBK)     s_start[b4] = ex;
    if (b4 + 1 < NBK) s_start[b4 + 1] = ex + p1;
    if (b4 + 2 < NBK) s_start[b4 + 2] = ex + p2;
    if (b4 + 3 < NBK) s_start[b4 + 3] = ex + p3;
    // reserve global runs
    for (int b = t; b < NBK; b += 256) {
        int c = s_cnt[b];
        s_gb[b] = (c > 0) ? atomicAdd(&bcursor[b], c) : 0;
    }
    __syncthreads();
    // place into sorted LDS image
#pragma unroll
    for (int i = 0; i < 8; ++i) {
        if (rec[i] < 0) continue;
        int e = e0 + i * 256 + t;
        int b = rec[i] & 1023;
        int dl = (rec[i] >> 10) & 255;
        int off = rec[i] >> 18;
        int pos = s_start[b] + off;
        s_img[pos] = ((uint32_t)dl << 18) | (uint32_t)__builtin_nontemporal_load(&src[e]);
        s_bkt[pos] = (uint16_t)b;
    }
    __syncthreads();
    // run-coalesced flush (consecutive i in a bucket -> consecutive global addrs)
    for (int i = t; i < cntblk; i += 256) {
        int b = s_bkt[i];
        int goff = s_gb[b] + (i - s_start[b]);
        if (goff < CAP) pairs[(size_t)b * CAP + goff] = s_img[i];
    }
}

// ---------------- pass B: per-bucket counting sort -> PADDED csr + meta/dis/xdh ----------
// R21: also zeroes this block's slice of pooled (removes it from memset span).
__global__ void __launch_bounds__(256) k_binB(
        const uint32_t* __restrict__ pairs, const int* __restrict__ bcursor,
        const float* __restrict__ x, int* __restrict__ csr_pad,
        int* __restrict__ csr_ovf, unsigned int* __restrict__ meta,
        float* __restrict__ dis, __half2* __restrict__ xdh,
        unsigned int* __restrict__ pooled, int npool, int n) {
    __shared__ int s_hist[NPB];
    __shared__ int s_start[NPB];
    __shared__ int s_wsum[4];
    __shared__ int s_pad[NPB * SLOTS];   // 16 KB padded image
    int b = blockIdx.x;
    int t = threadIdx.x;
    int lane = t & 63, wv = t >> 6;
    int cnt = min(bcursor[b], CAP);
    const uint32_t* pb = pairs + (size_t)b * CAP;
    s_hist[t] = 0;
    for (int i = t; i < NPB * SLOTS; i += 256) s_pad[i] = n;   // dummy fill
    // zero pooled slice: 31 entries per block covers 782*31 >= 24000
    {
        int pi = b * 31 + t;
        if (t < 31 && pi < npool) pooled[pi] = 0u;
    }
    __syncthreads();
    // single atomic pass -- histogram captures per-node arrival offset in regs
    uint32_t rdl[10];   // (off<<8) | dl ; sentinel 0xFFFFFFFF
    uint32_t rsx[10];   // src index
#pragma unroll
    for (int r = 0; r < 10; ++r) {
        int i = t + r * 256;
        rdl[r] = 0xFFFFFFFFu;
        if (i < cnt) {
            uint32_t p = __builtin_nontemporal_load(&pb[i]);
            int dl = (int)(p >> 18);
            int off = atomicAdd(&s_hist[dl], 1);
            rdl[r] = ((uint32_t)off << 8) | (uint32_t)dl;
            rsx[r] = p & 0x3FFFFu;
        }
    }
    __syncthreads();
    // exclusive scan of s_hist[256]: wave shfl scan + cross-wave combine
    int v = s_hist[t];
    int inc = v;
#pragma unroll
    for (int off = 1; off < 64; off <<= 1) {
        int u = __shfl_up(inc, off, 64);
        if (lane >= off) inc += u;
    }
    if (lane == 63) s_wsum[wv] = inc;
    __syncthreads();
    int wpre = 0;
#pragma unroll
    for (int w = 0; w < 3; ++w) wpre += (w < wv) ? s_wsum[w] : 0;
    s_start[t] = wpre + inc - v;
    __syncthreads();
    // meta + dis + xdh (1 node per thread, coalesced)
    int cb = b * CAP;                    // bucket-strided overflow base
    int node = (b << 8) + t;
    if (node < n) {
        int deg = s_hist[t];
        meta[node] = ((unsigned int)deg << 21) | (unsigned int)(cb + s_start[t]);
        float di = rsqrtf((float)(deg + 1));   // +1 self-loop
        dis[node] = di;
        const float4* xi = (const float4*)(x + (size_t)node * IN_DIM);
        float4 a = xi[0], c = xi[1];
        union { __half2 h[4]; int iv[4]; } u;
        u.h[0] = __float22half2_rn(make_float2(a.x * di, a.y * di));
        u.h[1] = __float22half2_rn(make_float2(a.z * di, a.w * di));
        u.h[2] = __float22half2_rn(make_float2(c.x * di, c.y * di));
        u.h[3] = __float22half2_rn(make_float2(c.z * di, c.w * di));
        ((int4*)xdh)[node] = make_int4(u.iv[0], u.iv[1], u.iv[2], u.iv[3]);
    } else if (node == n) {
        ((int4*)xdh)[n] = make_int4(0, 0, 0, 0);           // dummy zero row
    }
    // place: first 16 per node into LDS pad; overflow -> bucket-strided csr_ovf (rare)
#pragma unroll
    for (int r = 0; r < 10; ++r) {
        if (rdl[r] == 0xFFFFFFFFu) continue;
        int dl = (int)(rdl[r] & 255u);
        int pos = (int)(rdl[r] >> 8);
        int sidx = (int)rsx[r];
        if (pos < SLOTS) s_pad[dl * SLOTS + pos] = sidx;
        else             csr_ovf[cb + s_start[dl] + pos] = sidx;
    }
    __syncthreads();
    // coalesced int4 flush (guard phantom nodes past n)
    for (int i = t; i < NPB * SLOTS / 4; i += 256) {
        int node2 = (b << 8) + (i >> 2);
        if (node2 < n)
            ((int4*)csr_pad)[(size_t)(b << 8) * 4 + i] = ((int4*)s_pad)[i];
    }
}

// ---------------- fused agg1 + [grid barrier] + agg2/pool + [arrive] + head ----------
// LDS = 0; __launch_bounds__(256,3) -> 3 blocks/CU guaranteed -> 768 blocks
// co-resident -> spin barrier deadlock-free. Phase bodies identical to R20b.
__global__ void __launch_bounds__(256, 3) k_aggf(
        const int* __restrict__ csr_pad, const int* __restrict__ csr_ovf,
        const unsigned int* __restrict__ meta, const __half2* __restrict__ xdh,
        const float* __restrict__ dis, const float* __restrict__ W1,
        const float* __restrict__ b1, const float* __restrict__ W2,
        __half2* __restrict__ y2h, const float* __restrict__ b2,
        const int* __restrict__ batch, unsigned int* __restrict__ pooled,
        const float* __restrict__ Wl, const float* __restrict__ bl,
        float* __restrict__ out, unsigned int* __restrict__ bar, int n, int g) {
    int t = threadIdx.x;
    int lane = t & 63;

    // ================= phase 1: agg1 + MLP (register-batched gathers) ==========
    const int nt1 = (n + 1 + 255) / 256;             // 782 tiles (incl. dummy row)
    for (int tile = blockIdx.x; tile < nt1; tile += AGRID) {
        int node = tile * 256 + t;
        if (node > n) continue;
        int4* orow = (int4*)y2h + (size_t)node * 2;
        if (node == n) {                     // dummy zero row for agg2
            orow[0] = make_int4(0, 0, 0, 0);
            orow[1] = make_int4(0, 0, 0, 0);
            continue;
        }
        const int4* pr = (const int4*)(csr_pad + (size_t)node * SLOTS);
        int4 p0 = pr[0], p1 = pr[1], p2 = pr[2], p3 = pr[3];
        unsigned int m = meta[node];
        const int4* xt = (const int4*)xdh;

        int idx[16] = {p0.x, p0.y, p0.z, p0.w, p1.x, p1.y, p1.z, p1.w,
                       p2.x, p2.y, p2.z, p2.w, p3.x, p3.y, p3.z, p3.w};
        int4 r[17];
        r[0] = xt[node];                     // self-loop first
#pragma unroll
        for (int i = 0; i < 16; ++i) r[i + 1] = xt[(size_t)idx[i]];
        float acc[8] = {0, 0, 0, 0, 0, 0, 0, 0};
#pragma unroll
        for (int i = 0; i < 17; ++i) acc_row8(acc, r[i]);
        int deg = m >> 21;
        if (deg > SLOTS) {                   // rare overflow
            int r0 = (int)(m & 0x1FFFFF);
            for (int rr = SLOTS; rr < deg; ++rr) acc_row8(acc, xt[(size_t)csr_ovf[r0 + rr]]);
        }
        float di = dis[node];
        float z[8];
#pragma unroll
        for (int k = 0; k < 8; ++k) z[k] = acc[k] * di;

        float y2[H2];
#pragma unroll
        for (int j = 0; j < H2; ++j) y2[j] = 0.f;
        for (int d = 0; d < H1; ++d) {       // d wave-uniform -> s_load weights
            float h = b1[d];
#pragma unroll
            for (int k = 0; k < 8; ++k) h = fmaf(z[k], W1[k * H1 + d], h);
            h = fmaxf(h, 0.f);
#pragma unroll
            for (int j = 0; j < H2; ++j) y2[j] = fmaf(h, W2[d * H2 + j], y2[j]);
        }
        union { __half2 h2v[8]; int iv[8]; } u;
#pragma unroll
        for (int q = 0; q < 6; ++q)
            u.h2v[q] = __float22half2_rn(make_float2(y2[2 * q] * di, y2[2 * q + 1] * di));
        u.h2v[6] = __float22half2_rn(make_float2(0.f, 0.f));
        u.h2v[7] = u.h2v[6];
        orow[0] = make_int4(u.iv[0], u.iv[1], u.iv[2], u.iv[3]);
        orow[1] = make_int4(u.iv[4], u.iv[5], u.iv[6], u.iv[7]);
    }

    // ================= grid barrier A (all 768 blocks resident) ================
    __syncthreads();
    if (t == 0) {
        __threadfence();                           // flush y2h to device scope
        atomicAdd(&bar[0], 1u);
        while (atomicAdd(&bar[0], 0u) < (unsigned)AGRID)
            __builtin_amdgcn_s_sleep(8);
        __threadfence();                           // acquire: see all y2h
    }
    __syncthreads();

    // ================= phase 2: agg2 + fused segmented max-pool ================
    const int nt2 = (n + 255) / 256;                 // 782 tiles
    for (int tile = blockIdx.x; tile < nt2; tile += AGRID) {
        int node = tile * 256 + t;
        bool active = node < n;
        float v[12] = {0, 0, 0, 0, 0, 0, 0, 0, 0, 0, 0, 0};
        int gid = 0x7fffffff;
        if (active) {
            const int4* pr = (const int4*)(csr_pad + (size_t)node * SLOTS);
            int4 p0 = pr[0], p1 = pr[1], p2 = pr[2], p3 = pr[3];
            unsigned int m = meta[node];
            const int4* yt = (const int4*)y2h;   // 32B rows = 2 int4
            int idx[16] = {p0.x, p0.y, p0.z, p0.w, p1.x, p1.y, p1.z, p1.w,
                           p2.x, p2.y, p2.z, p2.w, p3.x, p3.y, p3.z, p3.w};
            float acc[12] = {0, 0, 0, 0, 0, 0, 0, 0, 0, 0, 0, 0};
            // batch 1: self + neighbors 0-7 (9 rows, 18 int4)
            int4 ra[9], rb[9];
            ra[0] = yt[(size_t)node * 2];
            rb[0] = yt[(size_t)node * 2 + 1];
#pragma unroll
            for (int i = 0; i < 8; ++i) {
                ra[i + 1] = yt[(size_t)idx[i] * 2];
                rb[i + 1] = yt[(size_t)idx[i] * 2 + 1];
            }
#pragma unroll
            for (int i = 0; i < 9; ++i) acc_row32(acc, ra[i], rb[i]);
            // batch 2: neighbors 8-15 (8 rows, 16 int4)
#pragma unroll
            for (int i = 0; i < 8; ++i) {
                ra[i] = yt[(size_t)idx[8 + i] * 2];
                rb[i] = yt[(size_t)idx[8 + i] * 2 + 1];
            }
#pragma unroll
            for (int i = 0; i < 8; ++i) acc_row32(acc, ra[i], rb[i]);
            int deg = m >> 21;
            if (deg > SLOTS) {                   // rare overflow
                int r0 = (int)(m & 0x1FFFFF);
                for (int rr = SLOTS; rr < deg; ++rr) {
                    int nb = csr_ovf[r0 + rr];
                    acc_row32(acc, yt[(size_t)nb * 2], yt[(size_t)nb * 2 + 1]);
                }
            }
            float di = dis[node];
#pragma unroll
            for (int q = 0; q < 12; ++q) v[q] = fmaxf(fmaf(acc[q], di, b2[q]), 0.f);
            gid = batch[node];
        }
        // wave segmented inclusive max-scan (batch sorted => segments contiguous)
#pragma unroll
        for (int off = 1; off < 64; off <<= 1) {
            int g2 = __shfl_up(gid, off, 64);
            bool merge = (lane >= off) && (g2 == gid);
#pragma unroll
            for (int q = 0; q < 12; ++q) {
                float tv = __shfl_up(v[q], off, 64);
                if (merge) v[q] = fmaxf(v[q], tv);
            }
        }
        int gnext = __shfl_down(gid, 1, 64);
        bool last = (lane == 63) || (gnext != gid);
        if (last && gid != 0x7fffffff) {
            unsigned int* pp = pooled + (size_t)gid * 12;
#pragma unroll
            for (int q = 0; q < 12; ++q) atomicMax(&pp[q], __float_as_uint(v[q]));
        }
    }

    // ================= arrive; block 0 waits and runs head =====================
    __syncthreads();
    if (t == 0) {
        __threadfence();                           // flush pooled atomics
        atomicAdd(&bar[1], 1u);
    }
    if (blockIdx.x == 0) {
        if (t == 0) {
            while (atomicAdd(&bar[1], 0u) < (unsigned)AGRID)
                __builtin_amdgcn_s_sleep(8);
            __threadfence();
        }
        __syncthreads();
        for (int i = t; i < g; i += 256) {
            float l0 = bl[0], l1 = bl[1];
#pragma unroll
            for (int k = 0; k < H2; ++k) {
                float pv = __uint_as_float(pooled[(size_t)i * 12 + k]);
                l0 = fmaf(pv, Wl[k * 2 + 0], l0);
                l1 = fmaf(pv, Wl[k * 2 + 1], l1);
            }
            float m = fmaxf(l0, l1);
            float lse = m + logf(expf(l0 - m) + expf(l1 - m));
            out[i * 2 + 0] = l0 - lse;
            out[i * 2 + 1] = l1 - lse;
        }
    }
}

extern "C" void kernel_launch(void* const* d_in, const int* in_sizes, int n_in,
                              void* d_out, int out_size, void* d_ws, size_t ws_size,
                              hipStream_t stream) {
    const float* x   = (const float*)d_in[0];
    const int* ei    = (const int*)d_in[1];
    const int* batch = (const int*)d_in[2];
    const float* W1  = (const float*)d_in[3];
    const float* b1  = (const float*)d_in[4];
    const float* W2  = (const float*)d_in[5];
    const float* b2  = (const float*)d_in[6];
    const float* Wl  = (const float*)d_in[7];
    const float* bl  = (const float*)d_in[8];
    float* out = (float*)d_out;

    const int N = in_sizes[0] / IN_DIM;   // 200000
    const int E = in_sizes[1] / 2;        // 1600000
    const int G = out_size / 2;           // 2000
    const int* src = ei;
    const int* dst = ei + E;

    auto cdiv = [](long long a, int b) { return (int)((a + b - 1) / b); };

    // workspace carve, 64B-aligned (bcursor+bar first: single tiny memset)
    char* wp = (char*)d_ws;
    auto carve = [&](size_t bytes) {
        char* p = wp;
        wp += (bytes + 63) & ~(size_t)63;
        return p;
    };
    int*          bcursor = (int*)carve(NBK * 4);
    unsigned int* bar     = (unsigned int*)carve(2 * 4);             // grid barrier
    unsigned int* pooled  = (unsigned int*)carve((size_t)G * H2 * 4); // zeroed in binB
    unsigned int* meta    = (unsigned int*)carve((size_t)N * 4);
    float*        dis     = (float*)carve((size_t)N * 4);
    __half2*      xdh     = (__half2*)carve((size_t)(N + 1) * 16);   // 16B rows
    __half2*      y2h     = (__half2*)carve((size_t)(N + 1) * 32);   // 32B rows
    uint32_t*     pairs   = (uint32_t*)carve((size_t)NBK * CAP * 4);
    int*          csr_pad = (int*)carve((size_t)N * SLOTS * 4);
    int*          csr_ovf = (int*)carve((size_t)NBK * CAP * 4);

    size_t zspan = (char*)(bar + 2) - (char*)bcursor;   // bcursor + bar only (~3.2KB)
    (void)hipMemsetAsync(bcursor, 0, zspan, stream);

    // CSR build (bucket-sorted binA -> padded csr in binB, fused meta/dis/xdh)
    k_binA<<<cdiv(E, CHUNK), 256, 0, stream>>>(src, dst, pairs, bcursor, E);
    k_binB<<<NBK, 256, 0, stream>>>(pairs, bcursor, x, csr_pad, csr_ovf,
                                    meta, dis, xdh, pooled, G * H2, N);

    // fused agg1 + grid-barrier + agg2/pool + head (768 co-resident blocks)
    k_aggf<<<AGRID, 256, 0, stream>>>(csr_pad, csr_ovf, meta, xdh, dis,
                                      W1, b1, W2, y2h, b2, batch, pooled,
                                      Wl, bl, out, bar, N, G);
}

// Round 11
// 197.777 us; speedup vs baseline: 1.4591x; 1.4591x over previous
//
#include <hip/hip_runtime.h>
#include <hip/hip_fp16.h>
#include <stdint.h>

// GCN: x[N,8] -> GCNConv(8,64)+ReLU -> GCNConv(64,12)+ReLU -> segment_max(G) -> @Wl+bl -> log_softmax
// N=200000, E=1600000, G=2000. fp32 params; indices int32.
//
// R22: harvest the last clean cuts. Budget (closed by R14/R19/R21 data):
// fill 45 (harness poison, in dur_us, fixed) | binA+binB 63 | agg1f 21 |
// agg2 ~42 | head+gaps ~5. agg kernels are outstanding-request-slot bound
// (~120 slots/CU model predicts 21/42us exactly) -> redistribution nulls.
// This round: (1) head FUSED into agg2 via last-block-done (atomicAdd
// arrival; only final block runs head; no grid-wide spin -- R21's skew bug
// avoided, R21 proved threadfence release/acquire works on this HW);
// (2) binB's 16-pass LDS dummy-fill deleted -- deg-clamp at flush instead;
// (3) pooled zeroed in binB, memset shrunk to bcursor+bar.
// R21 lesson: grid-stride + spin barrier = 2x skew; dispatch boundaries are
// CHEAP. R14: weight indices wave-uniform -> s_load. R19: node-parallel.
// Algebra (R3): xd=x*dis ; z[t]=dis[t]*(xd[t]+sum xd[src]) ;
// y2=(relu(z@W1+b1)@W2)*dis ; h2[t]=relu(dis[t]*(y2[t]+sum y2[src])+b2) ;
// pool-max per graph ; head.

constexpr int IN_DIM = 8;
constexpr int H1 = 64;
constexpr int H2 = 12;
constexpr int NPB = 256;      // nodes per bucket (bucket = dst >> 8)
constexpr int NBK = 782;      // ceil(200000 / 256)
constexpr int CAP = 2560;     // per-bucket capacity (avg 2048, sd ~45 -> 11 sigma)
constexpr int CHUNK = 2048;   // edges per binA block
constexpr int SLOTS = 16;     // padded csr slots per node

__device__ __forceinline__ void acc_row8(float* acc, int4 rv) {
    const __half2* h = (const __half2*)&rv;
#pragma unroll
    for (int q = 0; q < 4; ++q) {
        float2 f = __half22float2(h[q]);
        acc[2 * q] += f.x; acc[2 * q + 1] += f.y;
    }
}

__device__ __forceinline__ void acc_row32(float* acc, int4 ra, int4 rb) {
    const __half2* ha = (const __half2*)&ra;
    const __half2* hb = (const __half2*)&rb;
#pragma unroll
    for (int q = 0; q < 4; ++q) {
        float2 f = __half22float2(ha[q]);
        acc[2 * q] += f.x; acc[2 * q + 1] += f.y;
    }
#pragma unroll
    for (int q = 0; q < 2; ++q) {
        float2 f = __half22float2(hb[q]);
        acc[8 + 2 * q] += f.x; acc[9 + 2 * q] += f.y;
    }
}

// ---------------- pass A: bucket-sorted staging -> run-coalesced pair writes ----------
__global__ void __launch_bounds__(256) k_binA(
        const int* __restrict__ src, const int* __restrict__ dst,
        uint32_t* __restrict__ pairs, int* __restrict__ bcursor, int ne) {
    __shared__ int s_cnt[NBK];        // per-bucket count
    __shared__ int s_start[NBK];      // block-local exclusive starts
    __shared__ int s_gb[NBK];         // global run base
    __shared__ int s_wsum[4];         // per-wave scan totals
    __shared__ uint32_t s_img[CHUNK]; // bucket-sorted pairs (8 KB)
    __shared__ uint16_t s_bkt[CHUNK]; // bucket id per slot (4 KB)
    int t = threadIdx.x;
    int lane = t & 63, wv = t >> 6;
    for (int i = t; i < NBK; i += 256) s_cnt[i] = 0;
    __syncthreads();
    int e0 = blockIdx.x * CHUNK;
    int cntblk = min(CHUNK, ne - e0);
    int rec[8];
#pragma unroll
    for (int i = 0; i < 8; ++i) {
        int e = e0 + i * 256 + t;
        rec[i] = -1;
        if (e < ne) {
            int d = __builtin_nontemporal_load(&dst[e]);
            int b = d >> 8;                                  // 10 bits
            int off = atomicAdd(&s_cnt[b], 1);               // 11 bits
            rec[i] = (off << 18) | ((d & 255) << 10) | b;    // 12|8|10
        }
    }
    __syncthreads();
    // exclusive scan of s_cnt[782] (pad to 1024): wave shfl scan + combine
    int b4 = t * 4;
    int v0 = (b4 < NBK) ? s_cnt[b4] : 0;
    int v1 = (b4 + 1 < NBK) ? s_cnt[b4 + 1] : 0;
    int v2 = (b4 + 2 < NBK) ? s_cnt[b4 + 2] : 0;
    int v3 = (b4 + 3 < NBK) ? s_cnt[b4 + 3] : 0;
    int p1 = v0, p2 = v0 + v1, p3 = v0 + v1 + v2, tot = p3 + v3;
    int inc = tot;
#pragma unroll
    for (int off = 1; off < 64; off <<= 1) {
        int u = __shfl_up(inc, off, 64);
        if (lane >= off) inc += u;
    }
    if (lane == 63) s_wsum[wv] = inc;
    __syncthreads();
    int wpre = 0;
#pragma unroll
    for (int w = 0; w < 3; ++w) wpre += (w < wv) ? s_wsum[w] : 0;
    int ex = wpre + inc - tot;
    if (b4 < NBK)     s_start[b4] = ex;
    if (b4 + 1 < NBK) s_start[b4 + 1] = ex + p1;
    if (b4 + 2 < NBK) s_start[b4 + 2] = ex + p2;
    if (b4 + 3 < NBK) s_start[b4 + 3] = ex + p3;
    // reserve global runs
    for (int b = t; b < NBK; b += 256) {
        int c = s_cnt[b];
        s_gb[b] = (c > 0) ? atomicAdd(&bcursor[b], c) : 0;
    }
    __syncthreads();
    // place into sorted LDS image
#pragma unroll
    for (int i = 0; i < 8; ++i) {
        if (rec[i] < 0) continue;
        int e = e0 + i * 256 + t;
        int b = rec[i] & 1023;
        int dl = (rec[i] >> 10) & 255;
        int off = rec[i] >> 18;
        int pos = s_start[b] + off;
        s_img[pos] = ((uint32_t)dl << 18) | (uint32_t)__builtin_nontemporal_load(&src[e]);
        s_bkt[pos] = (uint16_t)b;
    }
    __syncthreads();
    // run-coalesced flush (consecutive i in a bucket -> consecutive global addrs)
    for (int i = t; i < cntblk; i += 256) {
        int b = s_bkt[i];
        int goff = s_gb[b] + (i - s_start[b]);
        if (goff < CAP) pairs[(size_t)b * CAP + goff] = s_img[i];
    }
}

// ---------------- pass B: per-bucket counting sort -> PADDED csr + meta/dis/xdh ----------
// R22: no dummy pre-fill (deg-clamp at flush); zeroes pooled slice.
__global__ void __launch_bounds__(256) k_binB(
        const uint32_t* __restrict__ pairs, const int* __restrict__ bcursor,
        const float* __restrict__ x, int* __restrict__ csr_pad,
        int* __restrict__ csr_ovf, unsigned int* __restrict__ meta,
        float* __restrict__ dis, __half2* __restrict__ xdh,
        unsigned int* __restrict__ pooled, int npool, int n) {
    __shared__ int s_hist[NPB];
    __shared__ int s_start[NPB];
    __shared__ int s_wsum[4];
    __shared__ int s_pad[NPB * SLOTS];   // 16 KB image (uninit; clamped at flush)
    int b = blockIdx.x;
    int t = threadIdx.x;
    int lane = t & 63, wv = t >> 6;
    int cnt = min(bcursor[b], CAP);
    const uint32_t* pb = pairs + (size_t)b * CAP;
    s_hist[t] = 0;
    // zero pooled slice: 31 entries per block covers 782*31 >= 24000
    {
        int pi = b * 31 + t;
        if (t < 31 && pi < npool) pooled[pi] = 0u;
    }
    __syncthreads();
    // single atomic pass -- histogram captures per-node arrival offset in regs
    uint32_t rdl[10];   // (off<<8) | dl ; sentinel 0xFFFFFFFF
    uint32_t rsx[10];   // src index
#pragma unroll
    for (int r = 0; r < 10; ++r) {
        int i = t + r * 256;
        rdl[r] = 0xFFFFFFFFu;
        if (i < cnt) {
            uint32_t p = __builtin_nontemporal_load(&pb[i]);
            int dl = (int)(p >> 18);
            int off = atomicAdd(&s_hist[dl], 1);
            rdl[r] = ((uint32_t)off << 8) | (uint32_t)dl;
            rsx[r] = p & 0x3FFFFu;
        }
    }
    __syncthreads();
    // exclusive scan of s_hist[256]: wave shfl scan + cross-wave combine
    int v = s_hist[t];
    int inc = v;
#pragma unroll
    for (int off = 1; off < 64; off <<= 1) {
        int u = __shfl_up(inc, off, 64);
        if (lane >= off) inc += u;
    }
    if (lane == 63) s_wsum[wv] = inc;
    __syncthreads();
    int wpre = 0;
#pragma unroll
    for (int w = 0; w < 3; ++w) wpre += (w < wv) ? s_wsum[w] : 0;
    s_start[t] = wpre + inc - v;
    __syncthreads();
    // meta + dis + xdh (1 node per thread, coalesced)
    int cb = b * CAP;                    // bucket-strided overflow base
    int node = (b << 8) + t;
    if (node < n) {
        int deg = s_hist[t];
        meta[node] = ((unsigned int)deg << 21) | (unsigned int)(cb + s_start[t]);
        float di = rsqrtf((float)(deg + 1));   // +1 self-loop
        dis[node] = di;
        const float4* xi = (const float4*)(x + (size_t)node * IN_DIM);
        float4 a = xi[0], c = xi[1];
        union { __half2 h[4]; int iv[4]; } u;
        u.h[0] = __float22half2_rn(make_float2(a.x * di, a.y * di));
        u.h[1] = __float22half2_rn(make_float2(a.z * di, a.w * di));
        u.h[2] = __float22half2_rn(make_float2(c.x * di, c.y * di));
        u.h[3] = __float22half2_rn(make_float2(c.z * di, c.w * di));
        ((int4*)xdh)[node] = make_int4(u.iv[0], u.iv[1], u.iv[2], u.iv[3]);
    } else if (node == n) {
        ((int4*)xdh)[n] = make_int4(0, 0, 0, 0);           // dummy zero row
    }
    // place: first 16 per node into LDS pad; overflow -> bucket-strided csr_ovf (rare)
#pragma unroll
    for (int r = 0; r < 10; ++r) {
        if (rdl[r] == 0xFFFFFFFFu) continue;
        int dl = (int)(rdl[r] & 255u);
        int pos = (int)(rdl[r] >> 8);
        int sidx = (int)rsx[r];
        if (pos < SLOTS) s_pad[dl * SLOTS + pos] = sidx;
        else             csr_ovf[cb + s_start[dl] + pos] = sidx;
    }
    __syncthreads();
    // coalesced int4 flush with deg-clamp (slots >= deg -> dummy node n)
    for (int i = t; i < NPB * SLOTS / 4; i += 256) {
        int nl = i >> 2;                  // node-local index
        int node2 = (b << 8) + nl;
        if (node2 >= n) continue;
        int deg2 = s_hist[nl];
        int base = (i & 3) * 4;
        int4 vq = ((int4*)s_pad)[i];      // may be uninit past deg -> clamped
        vq.x = (base + 0 < deg2) ? vq.x : n;
        vq.y = (base + 1 < deg2) ? vq.y : n;
        vq.z = (base + 2 < deg2) ? vq.z : n;
        vq.w = (base + 3 < deg2) ? vq.w : n;
        ((int4*)csr_pad)[(size_t)(b << 8) * 4 + i] = vq;
    }
}

// ---------------- agg1 + MLP fused: node per LANE, register-batched gathers ----------
__global__ void __launch_bounds__(256, 3) k_agg1f(
        const int* __restrict__ csr_pad, const int* __restrict__ csr_ovf,
        const unsigned int* __restrict__ meta, const __half2* __restrict__ xdh,
        const float* __restrict__ dis, const float* __restrict__ W1,
        const float* __restrict__ b1, const float* __restrict__ W2,
        __half2* __restrict__ y2h, int n) {
    int node = blockIdx.x * 256 + threadIdx.x;
    if (node > n) return;
    int4* orow = (int4*)y2h + (size_t)node * 2;
    if (node == n) {                     // dummy zero row for agg2
        orow[0] = make_int4(0, 0, 0, 0);
        orow[1] = make_int4(0, 0, 0, 0);
        return;
    }
    const int4* pr = (const int4*)(csr_pad + (size_t)node * SLOTS);
    int4 p0 = pr[0], p1 = pr[1], p2 = pr[2], p3 = pr[3];
    unsigned int m = meta[node];
    const int4* xt = (const int4*)xdh;

    int idx[16] = {p0.x, p0.y, p0.z, p0.w, p1.x, p1.y, p1.z, p1.w,
                   p2.x, p2.y, p2.z, p2.w, p3.x, p3.y, p3.z, p3.w};
    int4 r[17];
    r[0] = xt[node];                     // self-loop first
#pragma unroll
    for (int i = 0; i < 16; ++i) r[i + 1] = xt[(size_t)idx[i]];
    float acc[8] = {0, 0, 0, 0, 0, 0, 0, 0};
#pragma unroll
    for (int i = 0; i < 17; ++i) acc_row8(acc, r[i]);
    int deg = m >> 21;
    if (deg > SLOTS) {                   // rare overflow
        int r0 = (int)(m & 0x1FFFFF);
        for (int rr = SLOTS; rr < deg; ++rr) acc_row8(acc, xt[(size_t)csr_ovf[r0 + rr]]);
    }
    float di = dis[node];
    float z[8];
#pragma unroll
    for (int k = 0; k < 8; ++k) z[k] = acc[k] * di;

    float y2[H2];
#pragma unroll
    for (int j = 0; j < H2; ++j) y2[j] = 0.f;
    for (int d = 0; d < H1; ++d) {       // d wave-uniform -> s_load weights
        float h = b1[d];
#pragma unroll
        for (int k = 0; k < 8; ++k) h = fmaf(z[k], W1[k * H1 + d], h);
        h = fmaxf(h, 0.f);
#pragma unroll
        for (int j = 0; j < H2; ++j) y2[j] = fmaf(h, W2[d * H2 + j], y2[j]);
    }
    union { __half2 h2v[8]; int iv[8]; } u;
#pragma unroll
    for (int q = 0; q < 6; ++q)
        u.h2v[q] = __float22half2_rn(make_float2(y2[2 * q] * di, y2[2 * q + 1] * di));
    u.h2v[6] = __float22half2_rn(make_float2(0.f, 0.f));
    u.h2v[7] = u.h2v[6];
    orow[0] = make_int4(u.iv[0], u.iv[1], u.iv[2], u.iv[3]);
    orow[1] = make_int4(u.iv[4], u.iv[5], u.iv[6], u.iv[7]);
}

// ---------------- layer-2 agg + fused max-pool + LAST-BLOCK head ----------------
__global__ void __launch_bounds__(256, 3) k_agg2(
        const int* __restrict__ csr_pad, const int* __restrict__ csr_ovf,
        const unsigned int* __restrict__ meta, const __half2* __restrict__ y2h,
        const float* __restrict__ dis, const float* __restrict__ b2,
        const int* __restrict__ batch, unsigned int* __restrict__ pooled,
        const float* __restrict__ Wl, const float* __restrict__ bl,
        float* __restrict__ out, unsigned int* __restrict__ bar, int n, int g) {
    int node = blockIdx.x * 256 + threadIdx.x;
    int lane = threadIdx.x & 63;
    bool active = node < n;
    float v[12] = {0, 0, 0, 0, 0, 0, 0, 0, 0, 0, 0, 0};
    int gid = 0x7fffffff;
    if (active) {
        const int4* pr = (const int4*)(csr_pad + (size_t)node * SLOTS);
        int4 p0 = pr[0], p1 = pr[1], p2 = pr[2], p3 = pr[3];
        unsigned int m = meta[node];
        const int4* yt = (const int4*)y2h;   // 32B rows = 2 int4
        int idx[16] = {p0.x, p0.y, p0.z, p0.w, p1.x, p1.y, p1.z, p1.w,
                       p2.x, p2.y, p2.z, p2.w, p3.x, p3.y, p3.z, p3.w};
        float acc[12] = {0, 0, 0, 0, 0, 0, 0, 0, 0, 0, 0, 0};
        // batch 1: self + neighbors 0-7 (9 rows, 18 int4)
        int4 ra[9], rb[9];
        ra[0] = yt[(size_t)node * 2];
        rb[0] = yt[(size_t)node * 2 + 1];
#pragma unroll
        for (int i = 0; i < 8; ++i) {
            ra[i + 1] = yt[(size_t)idx[i] * 2];
            rb[i + 1] = yt[(size_t)idx[i] * 2 + 1];
        }
#pragma unroll
        for (int i = 0; i < 9; ++i) acc_row32(acc, ra[i], rb[i]);
        // batch 2: neighbors 8-15 (8 rows, 16 int4)
#pragma unroll
        for (int i = 0; i < 8; ++i) {
            ra[i] = yt[(size_t)idx[8 + i] * 2];
            rb[i] = yt[(size_t)idx[8 + i] * 2 + 1];
        }
#pragma unroll
        for (int i = 0; i < 8; ++i) acc_row32(acc, ra[i], rb[i]);
        int deg = m >> 21;
        if (deg > SLOTS) {                   // rare overflow
            int r0 = (int)(m & 0x1FFFFF);
            for (int rr = SLOTS; rr < deg; ++rr) {
                int nb = csr_ovf[r0 + rr];
                acc_row32(acc, yt[(size_t)nb * 2], yt[(size_t)nb * 2 + 1]);
            }
        }
        float di = dis[node];
#pragma unroll
        for (int q = 0; q < 12; ++q) v[q] = fmaxf(fmaf(acc[q], di, b2[q]), 0.f);
        gid = batch[node];
    }
    // wave segmented inclusive max-scan (batch sorted => segments contiguous)
#pragma unroll
    for (int off = 1; off < 64; off <<= 1) {
        int g2 = __shfl_up(gid, off, 64);
        bool merge = (lane >= off) && (g2 == gid);
#pragma unroll
        for (int q = 0; q < 12; ++q) {
            float tv = __shfl_up(v[q], off, 64);
            if (merge) v[q] = fmaxf(v[q], tv);
        }
    }
    int gnext = __shfl_down(gid, 1, 64);
    bool last = (lane == 63) || (gnext != gid);
    if (last && gid != 0x7fffffff) {
        unsigned int* pp = pooled + (size_t)gid * 12;
#pragma unroll
        for (int q = 0; q < 12; ++q) atomicMax(&pp[q], __float_as_uint(v[q]));
    }
    // -------- last-block-done: final arriving block runs the head --------
    __shared__ int s_last;
    __syncthreads();                       // drains this block's atomicMax ops
    if (threadIdx.x == 0) {
        __threadfence();                   // release (R21-verified fence path)
        unsigned old = atomicAdd(&bar[0], 1u);
        s_last = (old == (unsigned)(gridDim.x - 1)) ? 1 : 0;
    }
    __syncthreads();
    if (s_last) {
        if (threadIdx.x == 0) __threadfence();   // acquire
        __syncthreads();
        for (int i = threadIdx.x; i < g; i += 256) {
            float l0 = bl[0], l1 = bl[1];
#pragma unroll
            for (int k = 0; k < H2; ++k) {
                float pv = __uint_as_float(pooled[(size_t)i * 12 + k]);
                l0 = fmaf(pv, Wl[k * 2 + 0], l0);
                l1 = fmaf(pv, Wl[k * 2 + 1], l1);
            }
            float m = fmaxf(l0, l1);
            float lse = m + logf(expf(l0 - m) + expf(l1 - m));
            out[i * 2 + 0] = l0 - lse;
            out[i * 2 + 1] = l1 - lse;
        }
    }
}

extern "C" void kernel_launch(void* const* d_in, const int* in_sizes, int n_in,
                              void* d_out, int out_size, void* d_ws, size_t ws_size,
                              hipStream_t stream) {
    const float* x   = (const float*)d_in[0];
    const int* ei    = (const int*)d_in[1];
    const int* batch = (const int*)d_in[2];
    const float* W1  = (const float*)d_in[3];
    const float* b1  = (const float*)d_in[4];
    const float* W2  = (const float*)d_in[5];
    const float* b2  = (const float*)d_in[6];
    const float* Wl  = (const float*)d_in[7];
    const float* bl  = (const float*)d_in[8];
    float* out = (float*)d_out;

    const int N = in_sizes[0] / IN_DIM;   // 200000
    const int E = in_sizes[1] / 2;        // 1600000
    const int G = out_size / 2;           // 2000
    const int* src = ei;
    const int* dst = ei + E;

    auto cdiv = [](long long a, int b) { return (int)((a + b - 1) / b); };

    // workspace carve, 64B-aligned (bcursor+bar first: single tiny memset)
    char* wp = (char*)d_ws;
    auto carve = [&](size_t bytes) {
        char* p = wp;
        wp += (bytes + 63) & ~(size_t)63;
        return p;
    };
    int*          bcursor = (int*)carve(NBK * 4);
    unsigned int* bar     = (unsigned int*)carve(64);                 // arrival counter
    unsigned int* pooled  = (unsigned int*)carve((size_t)G * H2 * 4); // zeroed in binB
    unsigned int* meta    = (unsigned int*)carve((size_t)N * 4);
    float*        dis     = (float*)carve((size_t)N * 4);
    __half2*      xdh     = (__half2*)carve((size_t)(N + 1) * 16);   // 16B rows
    __half2*      y2h     = (__half2*)carve((size_t)(N + 1) * 32);   // 32B rows
    uint32_t*     pairs   = (uint32_t*)carve((size_t)NBK * CAP * 4);
    int*          csr_pad = (int*)carve((size_t)N * SLOTS * 4);
    int*          csr_ovf = (int*)carve((size_t)NBK * CAP * 4);

    size_t zspan = (char*)(bar) + 64 - (char*)bcursor;   // bcursor + bar (~3.2KB)
    (void)hipMemsetAsync(bcursor, 0, zspan, stream);

    // CSR build (bucket-sorted binA -> padded csr in binB, fused meta/dis/xdh)
    k_binA<<<cdiv(E, CHUNK), 256, 0, stream>>>(src, dst, pairs, bcursor, E);
    k_binB<<<NBK, 256, 0, stream>>>(pairs, bcursor, x, csr_pad, csr_ovf,
                                    meta, dis, xdh, pooled, G * H2, N);

    // fused layer-1 agg + MLP; layer-2 agg + pool + last-block head
    k_agg1f<<<cdiv((long long)N + 1, 256), 256, 0, stream>>>(
        csr_pad, csr_ovf, meta, xdh, dis, W1, b1, W2, y2h, N);
    k_agg2<<<cdiv(N, 256), 256, 0, stream>>>(csr_pad, csr_ovf, meta, y2h, dis, b2,
                                             batch, pooled, Wl, bl, out, bar, N, G);
}

// Round 12
// 173.377 us; speedup vs baseline: 1.6645x; 1.1407x over previous
//
#include <hip/hip_runtime.h>
#include <hip/hip_fp16.h>
#include <stdint.h>

// GCN: x[N,8] -> GCNConv(8,64)+ReLU -> GCNConv(64,12)+ReLU -> segment_max(G) -> @Wl+bl -> log_softmax
// N=200000, E=1600000, G=2000. fp32 params; indices int32.
//
// R23: REVERT to R20b (best measured: 174.99us). R22's two changes both
// regressed (+23us): per-block __threadfence before last-block-done head
// (gfx950 release fence = buffer_wbl2 L2 write-back x782 blocks; k_agg2
// 42->52.7us, hbm_gbps 390->1097) and binB deg-clamp flush. Closed budget:
// fill 45 (harness poison, untouchable) | binA+binB 63 (sort is right: R18
// scatter=140) | agg1f 21 + agg2 42 (outstanding-request-slot bound: R16/
// R17/R19/R20 redistribution nulls) | head+gaps 5 -> ~176 = measured floor.
// Algebra (R3): xd=x*dis ; z[t]=dis[t]*(xd[t]+sum xd[src]) ;
// y2=(relu(z@W1+b1)@W2)*dis ; h2[t]=relu(dis[t]*(y2[t]+sum y2[src])+b2) ;
// pool-max per graph ; head.
// R14 lesson: MLP weight indices wave-uniform -> s_load scalarization.
// R19 lesson: node-parallel gathers. R15: no coop launch. R21: no grid spin.
// R22 lesson: no per-block device-scope fences.

constexpr int IN_DIM = 8;
constexpr int H1 = 64;
constexpr int H2 = 12;
constexpr int NPB = 256;      // nodes per bucket (bucket = dst >> 8)
constexpr int NBK = 782;      // ceil(200000 / 256)
constexpr int CAP = 2560;     // per-bucket capacity (avg 2048, sd ~45 -> 11 sigma)
constexpr int CHUNK = 2048;   // edges per binA block
constexpr int SLOTS = 16;     // padded csr slots per node

__device__ __forceinline__ void acc_row8(float* acc, int4 rv) {
    const __half2* h = (const __half2*)&rv;
#pragma unroll
    for (int q = 0; q < 4; ++q) {
        float2 f = __half22float2(h[q]);
        acc[2 * q] += f.x; acc[2 * q + 1] += f.y;
    }
}

__device__ __forceinline__ void acc_row32(float* acc, int4 ra, int4 rb) {
    const __half2* ha = (const __half2*)&ra;
    const __half2* hb = (const __half2*)&rb;
#pragma unroll
    for (int q = 0; q < 4; ++q) {
        float2 f = __half22float2(ha[q]);
        acc[2 * q] += f.x; acc[2 * q + 1] += f.y;
    }
#pragma unroll
    for (int q = 0; q < 2; ++q) {
        float2 f = __half22float2(hb[q]);
        acc[8 + 2 * q] += f.x; acc[9 + 2 * q] += f.y;
    }
}

// ---------------- pass A: bucket-sorted staging -> run-coalesced pair writes ----------
__global__ void __launch_bounds__(256) k_binA(
        const int* __restrict__ src, const int* __restrict__ dst,
        uint32_t* __restrict__ pairs, int* __restrict__ bcursor, int ne) {
    __shared__ int s_cnt[NBK];        // per-bucket count
    __shared__ int s_start[NBK];      // block-local exclusive starts
    __shared__ int s_gb[NBK];         // global run base
    __shared__ int s_wsum[4];         // per-wave scan totals
    __shared__ uint32_t s_img[CHUNK]; // bucket-sorted pairs (8 KB)
    __shared__ uint16_t s_bkt[CHUNK]; // bucket id per slot (4 KB)
    int t = threadIdx.x;
    int lane = t & 63, wv = t >> 6;
    for (int i = t; i < NBK; i += 256) s_cnt[i] = 0;
    __syncthreads();
    int e0 = blockIdx.x * CHUNK;
    int cntblk = min(CHUNK, ne - e0);
    int rec[8];
#pragma unroll
    for (int i = 0; i < 8; ++i) {
        int e = e0 + i * 256 + t;
        rec[i] = -1;
        if (e < ne) {
            int d = __builtin_nontemporal_load(&dst[e]);
            int b = d >> 8;                                  // 10 bits
            int off = atomicAdd(&s_cnt[b], 1);               // 11 bits
            rec[i] = (off << 18) | ((d & 255) << 10) | b;    // 12|8|10
        }
    }
    __syncthreads();
    // exclusive scan of s_cnt[782] (pad to 1024), 4 elems/thread:
    // thread-local prefix + wave shfl scan + cross-wave combine (2 barriers)
    int b4 = t * 4;
    int v0 = (b4 < NBK) ? s_cnt[b4] : 0;
    int v1 = (b4 + 1 < NBK) ? s_cnt[b4 + 1] : 0;
    int v2 = (b4 + 2 < NBK) ? s_cnt[b4 + 2] : 0;
    int v3 = (b4 + 3 < NBK) ? s_cnt[b4 + 3] : 0;
    int p1 = v0, p2 = v0 + v1, p3 = v0 + v1 + v2, tot = p3 + v3;
    int inc = tot;
#pragma unroll
    for (int off = 1; off < 64; off <<= 1) {
        int u = __shfl_up(inc, off, 64);
        if (lane >= off) inc += u;
    }
    if (lane == 63) s_wsum[wv] = inc;
    __syncthreads();
    int wpre = 0;
#pragma unroll
    for (int w = 0; w < 3; ++w) wpre += (w < wv) ? s_wsum[w] : 0;
    int ex = wpre + inc - tot;
    if (b4 < NBK)     s_start[b4] = ex;
    if (b4 + 1 < NBK) s_start[b4 + 1] = ex + p1;
    if (b4 + 2 < NBK) s_start[b4 + 2] = ex + p2;
    if (b4 + 3 < NBK) s_start[b4 + 3] = ex + p3;
    // reserve global runs
    for (int b = t; b < NBK; b += 256) {
        int c = s_cnt[b];
        s_gb[b] = (c > 0) ? atomicAdd(&bcursor[b], c) : 0;
    }
    __syncthreads();
    // place into sorted LDS image
#pragma unroll
    for (int i = 0; i < 8; ++i) {
        if (rec[i] < 0) continue;
        int e = e0 + i * 256 + t;
        int b = rec[i] & 1023;
        int dl = (rec[i] >> 10) & 255;
        int off = rec[i] >> 18;
        int pos = s_start[b] + off;
        s_img[pos] = ((uint32_t)dl << 18) | (uint32_t)__builtin_nontemporal_load(&src[e]);
        s_bkt[pos] = (uint16_t)b;
    }
    __syncthreads();
    // run-coalesced flush (consecutive i in a bucket -> consecutive global addrs)
    for (int i = t; i < cntblk; i += 256) {
        int b = s_bkt[i];
        int goff = s_gb[b] + (i - s_start[b]);
        if (goff < CAP) pairs[(size_t)b * CAP + goff] = s_img[i];
    }
}

// ---------------- pass B: per-bucket counting sort -> PADDED csr + meta/dis/xdh ----------
__global__ void __launch_bounds__(256) k_binB(
        const uint32_t* __restrict__ pairs, const int* __restrict__ bcursor,
        const float* __restrict__ x, int* __restrict__ csr_pad,
        int* __restrict__ csr_ovf, unsigned int* __restrict__ meta,
        float* __restrict__ dis, __half2* __restrict__ xdh, int n) {
    __shared__ int s_hist[NPB];
    __shared__ int s_start[NPB];
    __shared__ int s_wsum[4];
    __shared__ int s_pad[NPB * SLOTS];   // 16 KB padded image
    int b = blockIdx.x;
    int t = threadIdx.x;
    int lane = t & 63, wv = t >> 6;
    int cnt = min(bcursor[b], CAP);
    const uint32_t* pb = pairs + (size_t)b * CAP;
    s_hist[t] = 0;
    for (int i = t; i < NPB * SLOTS; i += 256) s_pad[i] = n;   // dummy fill
    __syncthreads();
    // single atomic pass -- histogram captures per-node arrival offset in regs
    uint32_t rdl[10];   // (off<<8) | dl ; sentinel 0xFFFFFFFF
    uint32_t rsx[10];   // src index
#pragma unroll
    for (int r = 0; r < 10; ++r) {
        int i = t + r * 256;
        rdl[r] = 0xFFFFFFFFu;
        if (i < cnt) {
            uint32_t p = __builtin_nontemporal_load(&pb[i]);
            int dl = (int)(p >> 18);
            int off = atomicAdd(&s_hist[dl], 1);
            rdl[r] = ((uint32_t)off << 8) | (uint32_t)dl;
            rsx[r] = p & 0x3FFFFu;
        }
    }
    __syncthreads();
    // exclusive scan of s_hist[256]: wave shfl scan + cross-wave combine
    int v = s_hist[t];
    int inc = v;
#pragma unroll
    for (int off = 1; off < 64; off <<= 1) {
        int u = __shfl_up(inc, off, 64);
        if (lane >= off) inc += u;
    }
    if (lane == 63) s_wsum[wv] = inc;
    __syncthreads();
    int wpre = 0;
#pragma unroll
    for (int w = 0; w < 3; ++w) wpre += (w < wv) ? s_wsum[w] : 0;
    s_start[t] = wpre + inc - v;
    __syncthreads();
    // meta + dis + xdh (1 node per thread, coalesced)
    int cb = b * CAP;                    // bucket-strided overflow base
    int node = (b << 8) + t;
    if (node < n) {
        int deg = s_hist[t];
        meta[node] = ((unsigned int)deg << 21) | (unsigned int)(cb + s_start[t]);
        float di = rsqrtf((float)(deg + 1));   // +1 self-loop
        dis[node] = di;
        const float4* xi = (const float4*)(x + (size_t)node * IN_DIM);
        float4 a = xi[0], c = xi[1];
        union { __half2 h[4]; int iv[4]; } u;
        u.h[0] = __float22half2_rn(make_float2(a.x * di, a.y * di));
        u.h[1] = __float22half2_rn(make_float2(a.z * di, a.w * di));
        u.h[2] = __float22half2_rn(make_float2(c.x * di, c.y * di));
        u.h[3] = __float22half2_rn(make_float2(c.z * di, c.w * di));
        ((int4*)xdh)[node] = make_int4(u.iv[0], u.iv[1], u.iv[2], u.iv[3]);
    } else if (node == n) {
        ((int4*)xdh)[n] = make_int4(0, 0, 0, 0);           // dummy zero row
    }
    // place: first 16 per node into LDS pad; overflow -> bucket-strided csr_ovf (rare)
#pragma unroll
    for (int r = 0; r < 10; ++r) {
        if (rdl[r] == 0xFFFFFFFFu) continue;
        int dl = (int)(rdl[r] & 255u);
        int pos = (int)(rdl[r] >> 8);
        int sidx = (int)rsx[r];
        if (pos < SLOTS) s_pad[dl * SLOTS + pos] = sidx;
        else             csr_ovf[cb + s_start[dl] + pos] = sidx;
    }
    __syncthreads();
    // coalesced int4 flush (guard phantom nodes past n)
    for (int i = t; i < NPB * SLOTS / 4; i += 256) {
        int node2 = (b << 8) + (i >> 2);
        if (node2 < n)
            ((int4*)csr_pad)[(size_t)(b << 8) * 4 + i] = ((int4*)s_pad)[i];
    }
}

// ---------------- agg1 + MLP fused: node per LANE, register-batched gathers ----------
// All 17 int4 gathers issued before any consumption (68 VGPR in flight);
// __launch_bounds__(256,3): grid is work-limited at 3 waves/SIMD, so the
// higher VGPR cap (~170) costs no occupancy. Weights wave-uniform -> s_load.
__global__ void __launch_bounds__(256, 3) k_agg1f(
        const int* __restrict__ csr_pad, const int* __restrict__ csr_ovf,
        const unsigned int* __restrict__ meta, const __half2* __restrict__ xdh,
        const float* __restrict__ dis, const float* __restrict__ W1,
        const float* __restrict__ b1, const float* __restrict__ W2,
        __half2* __restrict__ y2h, int n) {
    int node = blockIdx.x * 256 + threadIdx.x;
    if (node > n) return;
    int4* orow = (int4*)y2h + (size_t)node * 2;
    if (node == n) {                     // dummy zero row for agg2
        orow[0] = make_int4(0, 0, 0, 0);
        orow[1] = make_int4(0, 0, 0, 0);
        return;
    }
    const int4* pr = (const int4*)(csr_pad + (size_t)node * SLOTS);
    int4 p0 = pr[0], p1 = pr[1], p2 = pr[2], p3 = pr[3];
    unsigned int m = meta[node];
    const int4* xt = (const int4*)xdh;

    int idx[16] = {p0.x, p0.y, p0.z, p0.w, p1.x, p1.y, p1.z, p1.w,
                   p2.x, p2.y, p2.z, p2.w, p3.x, p3.y, p3.z, p3.w};
    int4 r[17];
    r[0] = xt[node];                     // self-loop first (R14 order)
#pragma unroll
    for (int i = 0; i < 16; ++i) r[i + 1] = xt[(size_t)idx[i]];
    float acc[8] = {0, 0, 0, 0, 0, 0, 0, 0};
#pragma unroll
    for (int i = 0; i < 17; ++i) acc_row8(acc, r[i]);
    int deg = m >> 21;
    if (deg > SLOTS) {                   // rare overflow
        int r0 = (int)(m & 0x1FFFFF);
        for (int rr = SLOTS; rr < deg; ++rr) acc_row8(acc, xt[(size_t)csr_ovf[r0 + rr]]);
    }
    float di = dis[node];
    float z[8];
#pragma unroll
    for (int k = 0; k < 8; ++k) z[k] = acc[k] * di;

    float y2[H2];
#pragma unroll
    for (int j = 0; j < H2; ++j) y2[j] = 0.f;
    for (int d = 0; d < H1; ++d) {       // d wave-uniform -> s_load weights
        float h = b1[d];
#pragma unroll
        for (int k = 0; k < 8; ++k) h = fmaf(z[k], W1[k * H1 + d], h);
        h = fmaxf(h, 0.f);
#pragma unroll
        for (int j = 0; j < H2; ++j) y2[j] = fmaf(h, W2[d * H2 + j], y2[j]);
    }
    union { __half2 h2v[8]; int iv[8]; } u;
#pragma unroll
    for (int q = 0; q < 6; ++q)
        u.h2v[q] = __float22half2_rn(make_float2(y2[2 * q] * di, y2[2 * q + 1] * di));
    u.h2v[6] = __float22half2_rn(make_float2(0.f, 0.f));
    u.h2v[7] = u.h2v[6];
    orow[0] = make_int4(u.iv[0], u.iv[1], u.iv[2], u.iv[3]);
    orow[1] = make_int4(u.iv[4], u.iv[5], u.iv[6], u.iv[7]);
}

// ---------------- layer-2 aggregation + FUSED segmented max-pool ----------------
// Register-batched: two batches of 9/8 rows (18 int4 = 72 VGPR peak in flight),
// both 16B halves of each 32B row loaded back-to-back for line reuse.
__global__ void __launch_bounds__(256, 3) k_agg2(
        const int* __restrict__ csr_pad, const int* __restrict__ csr_ovf,
        const unsigned int* __restrict__ meta, const __half2* __restrict__ y2h,
        const float* __restrict__ dis, const float* __restrict__ b2,
        const int* __restrict__ batch, unsigned int* __restrict__ pooled, int n) {
    int node = blockIdx.x * 256 + threadIdx.x;
    int lane = threadIdx.x & 63;
    bool active = node < n;
    float v[12] = {0, 0, 0, 0, 0, 0, 0, 0, 0, 0, 0, 0};
    int gid = 0x7fffffff;
    if (active) {
        const int4* pr = (const int4*)(csr_pad + (size_t)node * SLOTS);
        int4 p0 = pr[0], p1 = pr[1], p2 = pr[2], p3 = pr[3];
        unsigned int m = meta[node];
        const int4* yt = (const int4*)y2h;   // 32B rows = 2 int4
        int idx[16] = {p0.x, p0.y, p0.z, p0.w, p1.x, p1.y, p1.z, p1.w,
                       p2.x, p2.y, p2.z, p2.w, p3.x, p3.y, p3.z, p3.w};
        float acc[12] = {0, 0, 0, 0, 0, 0, 0, 0, 0, 0, 0, 0};
        // batch 1: self + neighbors 0-7 (9 rows, 18 int4)
        int4 ra[9], rb[9];
        ra[0] = yt[(size_t)node * 2];
        rb[0] = yt[(size_t)node * 2 + 1];
#pragma unroll
        for (int i = 0; i < 8; ++i) {
            ra[i + 1] = yt[(size_t)idx[i] * 2];
            rb[i + 1] = yt[(size_t)idx[i] * 2 + 1];
        }
#pragma unroll
        for (int i = 0; i < 9; ++i) acc_row32(acc, ra[i], rb[i]);
        // batch 2: neighbors 8-15 (8 rows, 16 int4)
#pragma unroll
        for (int i = 0; i < 8; ++i) {
            ra[i] = yt[(size_t)idx[8 + i] * 2];
            rb[i] = yt[(size_t)idx[8 + i] * 2 + 1];
        }
#pragma unroll
        for (int i = 0; i < 8; ++i) acc_row32(acc, ra[i], rb[i]);
        int deg = m >> 21;
        if (deg > SLOTS) {                   // rare overflow
            int r0 = (int)(m & 0x1FFFFF);
            for (int rr = SLOTS; rr < deg; ++rr) {
                int nb = csr_ovf[r0 + rr];
                acc_row32(acc, yt[(size_t)nb * 2], yt[(size_t)nb * 2 + 1]);
            }
        }
        float di = dis[node];
#pragma unroll
        for (int q = 0; q < 12; ++q) v[q] = fmaxf(fmaf(acc[q], di, b2[q]), 0.f);
        gid = batch[node];
    }
    // wave segmented inclusive max-scan (batch sorted => segments contiguous)
#pragma unroll
    for (int off = 1; off < 64; off <<= 1) {
        int g2 = __shfl_up(gid, off, 64);
        bool merge = (lane >= off) && (g2 == gid);
#pragma unroll
        for (int q = 0; q < 12; ++q) {
            float tv = __shfl_up(v[q], off, 64);
            if (merge) v[q] = fmaxf(v[q], tv);
        }
    }
    int gnext = __shfl_down(gid, 1, 64);
    bool last = (lane == 63) || (gnext != gid);
    if (last && gid != 0x7fffffff) {
        unsigned int* pp = pooled + (size_t)gid * 12;
#pragma unroll
        for (int q = 0; q < 12; ++q) atomicMax(&pp[q], __float_as_uint(v[q]));
    }
}

// ---------------- head: logits + log_softmax from pooled ----------------
__global__ void k_head(const unsigned int* __restrict__ pooled,
                       const float* __restrict__ Wl, const float* __restrict__ bl,
                       float* __restrict__ out, int g) {
    int i = blockIdx.x * 256 + threadIdx.x;
    if (i >= g) return;
    float l0 = bl[0], l1 = bl[1];
#pragma unroll
    for (int k = 0; k < H2; ++k) {
        float pv = __uint_as_float(pooled[(size_t)i * 12 + k]);
        l0 = fmaf(pv, Wl[k * 2 + 0], l0);
        l1 = fmaf(pv, Wl[k * 2 + 1], l1);
    }
    float m = fmaxf(l0, l1);
    float lse = m + logf(expf(l0 - m) + expf(l1 - m));
    out[i * 2 + 0] = l0 - lse;
    out[i * 2 + 1] = l1 - lse;
}

extern "C" void kernel_launch(void* const* d_in, const int* in_sizes, int n_in,
                              void* d_out, int out_size, void* d_ws, size_t ws_size,
                              hipStream_t stream) {
    const float* x   = (const float*)d_in[0];
    const int* ei    = (const int*)d_in[1];
    const int* batch = (const int*)d_in[2];
    const float* W1  = (const float*)d_in[3];
    const float* b1  = (const float*)d_in[4];
    const float* W2  = (const float*)d_in[5];
    const float* b2  = (const float*)d_in[6];
    const float* Wl  = (const float*)d_in[7];
    const float* bl  = (const float*)d_in[8];
    float* out = (float*)d_out;

    const int N = in_sizes[0] / IN_DIM;   // 200000
    const int E = in_sizes[1] / 2;        // 1600000
    const int G = out_size / 2;           // 2000
    const int* src = ei;
    const int* dst = ei + E;

    auto cdiv = [](long long a, int b) { return (int)((a + b - 1) / b); };

    // workspace carve, 64B-aligned (bcursor+pooled first: single zeroing memset)
    char* wp = (char*)d_ws;
    auto carve = [&](size_t bytes) {
        char* p = wp;
        wp += (bytes + 63) & ~(size_t)63;
        return p;
    };
    int*          bcursor = (int*)carve(NBK * 4);
    unsigned int* pooled  = (unsigned int*)carve((size_t)G * H2 * 4);
    unsigned int* meta    = (unsigned int*)carve((size_t)N * 4);
    float*        dis     = (float*)carve((size_t)N * 4);
    __half2*      xdh     = (__half2*)carve((size_t)(N + 1) * 16);   // 16B rows
    __half2*      y2h     = (__half2*)carve((size_t)(N + 1) * 32);   // 32B rows
    uint32_t*     pairs   = (uint32_t*)carve((size_t)NBK * CAP * 4);
    int*          csr_pad = (int*)carve((size_t)N * SLOTS * 4);
    int*          csr_ovf = (int*)carve((size_t)NBK * CAP * 4);

    size_t zspan = (char*)(pooled + (size_t)G * H2) - (char*)bcursor;
    (void)hipMemsetAsync(bcursor, 0, zspan, stream);

    // CSR build (bucket-sorted binA -> padded csr in binB, fused meta/dis/xdh)
    k_binA<<<cdiv(E, CHUNK), 256, 0, stream>>>(src, dst, pairs, bcursor, E);
    k_binB<<<NBK, 256, 0, stream>>>(pairs, bcursor, x, csr_pad, csr_ovf,
                                    meta, dis, xdh, N);

    // fused layer-1 agg + MLP, layer-2 agg + fused pool, head
    k_agg1f<<<cdiv((long long)N + 1, 256), 256, 0, stream>>>(
        csr_pad, csr_ovf, meta, xdh, dis, W1, b1, W2, y2h, N);
    k_agg2<<<cdiv(N, 256), 256, 0, stream>>>(csr_pad, csr_ovf, meta, y2h, dis, b2,
                                             batch, pooled, N);
    k_head<<<cdiv(G, 256), 256, 0, stream>>>(pooled, Wl, bl, out, G);
}